// Round 1
// baseline (287.624 us; speedup 1.0000x reference)
//
#include <hip/hip_runtime.h>
#include <hip/hip_bf16.h>

#define B 64
#define S 512
#define H 1024
#define HID 512
#define EPS 1e-5f

// ---------------------------------------------------------------------------
// K1: span means + pronoun gather -> x (B x 3H), x[b] = [emb_a | emb_b | emb_p]
// grid (B, 3), block (256, 4). Each thread owns 4 channels (float4), ty strides s.
// ---------------------------------------------------------------------------
__global__ __launch_bounds__(1024) void span_kernel(
    const float* __restrict__ bert, const int* __restrict__ offsets,
    float* __restrict__ x) {
    const int b  = blockIdx.x;
    const int e  = blockIdx.y;          // 0 = span a, 1 = span b, 2 = pronoun
    const int tx = threadIdx.x;         // 0..255  -> channel group
    const int ty = threadIdx.y;         // 0..3    -> s stride

    int start, end;
    if (e == 0)      { start = offsets[b * 5 + 0]; end = offsets[b * 5 + 1]; }
    else if (e == 1) { start = offsets[b * 5 + 2]; end = offsets[b * 5 + 3]; }
    else             { start = offsets[b * 5 + 4]; end = start; }

    float4 acc = make_float4(0.f, 0.f, 0.f, 0.f);
    const size_t brow = (size_t)b * S;
    for (int s = start + ty; s <= end; s += 4) {
        const float4 v = *reinterpret_cast<const float4*>(
            bert + (brow + (size_t)s) * H + tx * 4);
        acc.x += v.x; acc.y += v.y; acc.z += v.z; acc.w += v.w;
    }

    __shared__ float4 red[4][256];
    red[ty][tx] = acc;
    __syncthreads();

    if (ty == 0) {
        float4 a0 = red[0][tx], a1 = red[1][tx], a2 = red[2][tx], a3 = red[3][tx];
        const float inv = 1.0f / (float)(end - start + 1);
        float4 r;
        r.x = (a0.x + a1.x + a2.x + a3.x) * inv;
        r.y = (a0.y + a1.y + a2.y + a3.y) * inv;
        r.z = (a0.z + a1.z + a2.z + a3.z) * inv;
        r.w = (a0.w + a1.w + a2.w + a3.w) * inv;
        *reinterpret_cast<float4*>(x + (size_t)b * (3 * H) + e * H + tx * 4) = r;
    }
}

// ---------------------------------------------------------------------------
// K2: h += x(64x3072) @ W1(3072x512), split-K with atomics.
// grid (8 N-tiles, 16 K-chunks of 192), block 256.
// Thread = (jg = tid&15 -> 4 j's, mg = tid>>4 -> 4 m's); 4x4 register tile.
// ---------------------------------------------------------------------------
#define KCH 192
__global__ __launch_bounds__(256) void gemm1_kernel(
    const float* __restrict__ x, const float* __restrict__ W1,
    float* __restrict__ h) {
    const int jg = threadIdx.x & 15;
    const int mg = threadIdx.x >> 4;
    const int jbase = blockIdx.x * 64 + jg * 4;
    const int kbase = blockIdx.y * KCH;

    float acc[4][4];
#pragma unroll
    for (int i = 0; i < 4; ++i)
#pragma unroll
        for (int j = 0; j < 4; ++j) acc[i][j] = 0.f;

    const int m0 = mg * 4;
    for (int k = kbase; k < kbase + KCH; k += 4) {
        float4 wv[4];
#pragma unroll
        for (int kc = 0; kc < 4; ++kc)
            wv[kc] = *reinterpret_cast<const float4*>(W1 + (size_t)(k + kc) * HID + jbase);
        float4 xv[4];
#pragma unroll
        for (int mi = 0; mi < 4; ++mi)
            xv[mi] = *reinterpret_cast<const float4*>(x + (size_t)(m0 + mi) * (3 * H) + k);
#pragma unroll
        for (int mi = 0; mi < 4; ++mi) {
            acc[mi][0] += xv[mi].x * wv[0].x + xv[mi].y * wv[1].x + xv[mi].z * wv[2].x + xv[mi].w * wv[3].x;
            acc[mi][1] += xv[mi].x * wv[0].y + xv[mi].y * wv[1].y + xv[mi].z * wv[2].y + xv[mi].w * wv[3].y;
            acc[mi][2] += xv[mi].x * wv[0].z + xv[mi].y * wv[1].z + xv[mi].z * wv[2].z + xv[mi].w * wv[3].z;
            acc[mi][3] += xv[mi].x * wv[0].w + xv[mi].y * wv[1].w + xv[mi].z * wv[2].w + xv[mi].w * wv[3].w;
        }
    }

#pragma unroll
    for (int mi = 0; mi < 4; ++mi)
#pragma unroll
        for (int ji = 0; ji < 4; ++ji)
            atomicAdd(&h[(size_t)(m0 + mi) * HID + jbase + ji], acc[mi][ji]);
}

// ---------------------------------------------------------------------------
// K3: out[b] = leaky(BN(h[b] + b1)) @ W2 + b2. grid B, block 256.
// ---------------------------------------------------------------------------
__global__ __launch_bounds__(256) void head_kernel(
    const float* __restrict__ h, const float* __restrict__ b1,
    const float* __restrict__ gamma, const float* __restrict__ beta,
    const float* __restrict__ rm, const float* __restrict__ rv,
    const float* __restrict__ W2, const float* __restrict__ b2,
    float* __restrict__ out) {
    const int b = blockIdx.x;
    const int t = threadIdx.x;

    float c0 = 0.f, c1 = 0.f, c2 = 0.f;
    for (int j = t; j < HID; j += 256) {
        float v = (h[(size_t)b * HID + j] + b1[j] - rm[j]) * rsqrtf(rv[j] + EPS) * gamma[j] + beta[j];
        v = (v >= 0.f) ? v : 0.01f * v;
        c0 += v * W2[j * 3 + 0];
        c1 += v * W2[j * 3 + 1];
        c2 += v * W2[j * 3 + 2];
    }
#pragma unroll
    for (int off = 32; off > 0; off >>= 1) {
        c0 += __shfl_down(c0, off);
        c1 += __shfl_down(c1, off);
        c2 += __shfl_down(c2, off);
    }
    __shared__ float red[4][3];
    const int lane = t & 63, w = t >> 6;
    if (lane == 0) { red[w][0] = c0; red[w][1] = c1; red[w][2] = c2; }
    __syncthreads();
    if (t == 0) {
        out[b * 3 + 0] = red[0][0] + red[1][0] + red[2][0] + red[3][0] + b2[0];
        out[b * 3 + 1] = red[0][1] + red[1][1] + red[2][1] + red[3][1] + b2[1];
        out[b * 3 + 2] = red[0][2] + red[1][2] + red[2][2] + red[3][2] + b2[2];
    }
}

extern "C" void kernel_launch(void* const* d_in, const int* in_sizes, int n_in,
                              void* d_out, int out_size, void* d_ws, size_t ws_size,
                              hipStream_t stream) {
    const float* bert    = (const float*)d_in[0];
    const int*   offsets = (const int*)d_in[1];
    const float* W1      = (const float*)d_in[2];
    const float* b1      = (const float*)d_in[3];
    const float* gamma   = (const float*)d_in[4];
    const float* beta    = (const float*)d_in[5];
    const float* rm      = (const float*)d_in[6];
    const float* rv      = (const float*)d_in[7];
    const float* W2      = (const float*)d_in[8];
    const float* b2      = (const float*)d_in[9];
    float* out = (float*)d_out;

    float* x = (float*)d_ws;                                   // B x 3H = 768 KB
    float* h = (float*)((char*)d_ws + (size_t)B * 3 * H * 4);  // B x HID = 128 KB

    hipMemsetAsync(h, 0, (size_t)B * HID * sizeof(float), stream);

    dim3 g1(B, 3), t1(256, 4);
    span_kernel<<<g1, t1, 0, stream>>>(bert, offsets, x);

    dim3 g2(HID / 64, (3 * H) / KCH), t2(256);
    gemm1_kernel<<<g2, t2, 0, stream>>>(x, W1, h);

    head_kernel<<<B, 256, 0, stream>>>(h, b1, gamma, beta, rm, rv, W2, b2, out);
}

// Round 2
// 254.032 us; speedup vs baseline: 1.1322x; 1.1322x over previous
//
#include <hip/hip_runtime.h>
#include <hip/hip_bf16.h>

#define B 64
#define S 512
#define H 1024
#define HID 512
#define EPS 1e-5f
#define SCHUNK 64                 // rows per span chunk
#define NCH (S / SCHUNK)          // 8 chunks

// ---------------------------------------------------------------------------
// K1: load-balanced span means + pronoun gather -> x (B x 3H), pre-scaled.
// grid (B, 3, NCH), block 256. Thread tx owns channels [tx*4, tx*4+4).
// Each block covers [start,end] ∩ [c*64, c*64+63], accumulates, and
// atomicAdds acc/len into x. x must be pre-zeroed.
// ---------------------------------------------------------------------------
__global__ __launch_bounds__(256) void span_kernel(
    const float* __restrict__ bert, const int* __restrict__ offsets,
    float* __restrict__ x) {
    const int b = blockIdx.x;
    const int e = blockIdx.y;            // 0 = span a, 1 = span b, 2 = pronoun
    const int c = blockIdx.z;            // s-chunk

    int start, end;
    if (e == 0)      { start = offsets[b * 5 + 0]; end = offsets[b * 5 + 1]; }
    else if (e == 1) { start = offsets[b * 5 + 2]; end = offsets[b * 5 + 3]; }
    else             { start = offsets[b * 5 + 4]; end = start; }

    const int lo = max(start, c * SCHUNK);
    const int hi = min(end, c * SCHUNK + SCHUNK - 1);
    if (lo > hi) return;

    const float inv = 1.0f / (float)(end - start + 1);
    const int tx = threadIdx.x;

    float4 acc = make_float4(0.f, 0.f, 0.f, 0.f);
    const float* p = bert + ((size_t)b * S + lo) * H + tx * 4;
#pragma unroll 4
    for (int s = lo; s <= hi; ++s, p += H) {
        const float4 v = *reinterpret_cast<const float4*>(p);
        acc.x += v.x; acc.y += v.y; acc.z += v.z; acc.w += v.w;
    }

    float* xp = x + (size_t)b * (3 * H) + e * H + tx * 4;
    atomicAdd(xp + 0, acc.x * inv);
    atomicAdd(xp + 1, acc.y * inv);
    atomicAdd(xp + 2, acc.z * inv);
    atomicAdd(xp + 3, acc.w * inv);
}

// ---------------------------------------------------------------------------
// K2: h += x(64x3072) @ W1(3072x512), split-K with atomics.
// grid (8 N-tiles, 16 K-chunks of 192), block 256.
// Thread = (jg = tid&15 -> 4 j's, mg = tid>>4 -> 4 m's); 4x4 register tile.
// h must be pre-zeroed.
// ---------------------------------------------------------------------------
#define KCH 192
__global__ __launch_bounds__(256) void gemm1_kernel(
    const float* __restrict__ x, const float* __restrict__ W1,
    float* __restrict__ h) {
    const int jg = threadIdx.x & 15;
    const int mg = threadIdx.x >> 4;
    const int jbase = blockIdx.x * 64 + jg * 4;
    const int kbase = blockIdx.y * KCH;

    float acc[4][4];
#pragma unroll
    for (int i = 0; i < 4; ++i)
#pragma unroll
        for (int j = 0; j < 4; ++j) acc[i][j] = 0.f;

    const int m0 = mg * 4;
    for (int k = kbase; k < kbase + KCH; k += 4) {
        float4 wv[4];
#pragma unroll
        for (int kc = 0; kc < 4; ++kc)
            wv[kc] = *reinterpret_cast<const float4*>(W1 + (size_t)(k + kc) * HID + jbase);
        float4 xv[4];
#pragma unroll
        for (int mi = 0; mi < 4; ++mi)
            xv[mi] = *reinterpret_cast<const float4*>(x + (size_t)(m0 + mi) * (3 * H) + k);
#pragma unroll
        for (int mi = 0; mi < 4; ++mi) {
            acc[mi][0] += xv[mi].x * wv[0].x + xv[mi].y * wv[1].x + xv[mi].z * wv[2].x + xv[mi].w * wv[3].x;
            acc[mi][1] += xv[mi].x * wv[0].y + xv[mi].y * wv[1].y + xv[mi].z * wv[2].y + xv[mi].w * wv[3].y;
            acc[mi][2] += xv[mi].x * wv[0].z + xv[mi].y * wv[1].z + xv[mi].z * wv[2].z + xv[mi].w * wv[3].z;
            acc[mi][3] += xv[mi].x * wv[0].w + xv[mi].y * wv[1].w + xv[mi].z * wv[2].w + xv[mi].w * wv[3].w;
        }
    }

#pragma unroll
    for (int mi = 0; mi < 4; ++mi)
#pragma unroll
        for (int ji = 0; ji < 4; ++ji)
            atomicAdd(&h[(size_t)(m0 + mi) * HID + jbase + ji], acc[mi][ji]);
}

// ---------------------------------------------------------------------------
// K3: out[b] = leaky(BN(h[b] + b1)) @ W2 + b2. grid B, block 256.
// ---------------------------------------------------------------------------
__global__ __launch_bounds__(256) void head_kernel(
    const float* __restrict__ h, const float* __restrict__ b1,
    const float* __restrict__ gamma, const float* __restrict__ beta,
    const float* __restrict__ rm, const float* __restrict__ rv,
    const float* __restrict__ W2, const float* __restrict__ b2,
    float* __restrict__ out) {
    const int b = blockIdx.x;
    const int t = threadIdx.x;

    float c0 = 0.f, c1 = 0.f, c2 = 0.f;
    for (int j = t; j < HID; j += 256) {
        float v = (h[(size_t)b * HID + j] + b1[j] - rm[j]) * rsqrtf(rv[j] + EPS) * gamma[j] + beta[j];
        v = (v >= 0.f) ? v : 0.01f * v;
        c0 += v * W2[j * 3 + 0];
        c1 += v * W2[j * 3 + 1];
        c2 += v * W2[j * 3 + 2];
    }
#pragma unroll
    for (int off = 32; off > 0; off >>= 1) {
        c0 += __shfl_down(c0, off);
        c1 += __shfl_down(c1, off);
        c2 += __shfl_down(c2, off);
    }
    __shared__ float red[4][3];
    const int lane = t & 63, w = t >> 6;
    if (lane == 0) { red[w][0] = c0; red[w][1] = c1; red[w][2] = c2; }
    __syncthreads();
    if (t == 0) {
        out[b * 3 + 0] = red[0][0] + red[1][0] + red[2][0] + red[3][0] + b2[0];
        out[b * 3 + 1] = red[0][1] + red[1][1] + red[2][1] + red[3][1] + b2[1];
        out[b * 3 + 2] = red[0][2] + red[1][2] + red[2][2] + red[3][2] + b2[2];
    }
}

extern "C" void kernel_launch(void* const* d_in, const int* in_sizes, int n_in,
                              void* d_out, int out_size, void* d_ws, size_t ws_size,
                              hipStream_t stream) {
    const float* bert    = (const float*)d_in[0];
    const int*   offsets = (const int*)d_in[1];
    const float* W1      = (const float*)d_in[2];
    const float* b1      = (const float*)d_in[3];
    const float* gamma   = (const float*)d_in[4];
    const float* beta    = (const float*)d_in[5];
    const float* rm      = (const float*)d_in[6];
    const float* rv      = (const float*)d_in[7];
    const float* W2      = (const float*)d_in[8];
    const float* b2      = (const float*)d_in[9];
    float* out = (float*)d_out;

    float* x = (float*)d_ws;                                   // B x 3H = 768 KB
    float* h = (float*)((char*)d_ws + (size_t)B * 3 * H * 4);  // B x HID = 128 KB

    // zero x and h in one contiguous memset (they are adjacent in ws)
    hipMemsetAsync(d_ws, 0, (size_t)(B * 3 * H + B * HID) * sizeof(float), stream);

    dim3 g1(B, 3, NCH), t1(256);
    span_kernel<<<g1, t1, 0, stream>>>(bert, offsets, x);

    dim3 g2(HID / 64, (3 * H) / KCH), t2(256);
    gemm1_kernel<<<g2, t2, 0, stream>>>(x, W1, h);

    head_kernel<<<B, 256, 0, stream>>>(h, b1, gamma, beta, rm, rv, W2, b2, out);
}

// Round 5
// 251.004 us; speedup vs baseline: 1.1459x; 1.0121x over previous
//
#include <hip/hip_runtime.h>
#include <hip/hip_bf16.h>

#define B 64
#define S 512
#define H 1024
#define HID 512
#define EPS 1e-5f
#define SCHUNK 16                 // rows per span chunk (fine-grained for balance)
#define NCH (S / SCHUNK)          // 32 chunks

// ---------------------------------------------------------------------------
// K1: load-balanced span means + pronoun gather -> x (B x 3H), pre-scaled.
// grid (B, 3, NCH), block 256. Thread tx owns channels [tx*4, tx*4+4).
// Each block covers [start,end] ∩ [c*16, c*16+15], accumulates, and
// atomicAdds acc/len into x. x must be pre-zeroed.
// ---------------------------------------------------------------------------
__global__ __launch_bounds__(256) void span_kernel(
    const float* __restrict__ bert, const int* __restrict__ offsets,
    float* __restrict__ x) {
    const int b = blockIdx.x;
    const int e = blockIdx.y;            // 0 = span a, 1 = span b, 2 = pronoun
    const int c = blockIdx.z;            // s-chunk

    int start, end;
    if (e == 0)      { start = offsets[b * 5 + 0]; end = offsets[b * 5 + 1]; }
    else if (e == 1) { start = offsets[b * 5 + 2]; end = offsets[b * 5 + 3]; }
    else             { start = offsets[b * 5 + 4]; end = start; }

    const int lo = max(start, c * SCHUNK);
    const int hi = min(end, c * SCHUNK + SCHUNK - 1);
    if (lo > hi) return;

    const float inv = 1.0f / (float)(end - start + 1);
    const int tx = threadIdx.x;

    float4 acc = make_float4(0.f, 0.f, 0.f, 0.f);
    const float* p = bert + ((size_t)b * S + lo) * H + tx * 4;
#pragma unroll 4
    for (int s = lo; s <= hi; ++s, p += H) {
        const float4 v = *reinterpret_cast<const float4*>(p);
        acc.x += v.x; acc.y += v.y; acc.z += v.z; acc.w += v.w;
    }

    float* xp = x + (size_t)b * (3 * H) + e * H + tx * 4;
    atomicAdd(xp + 0, acc.x * inv);
    atomicAdd(xp + 1, acc.y * inv);
    atomicAdd(xp + 2, acc.z * inv);
    atomicAdd(xp + 3, acc.w * inv);
}

// ---------------------------------------------------------------------------
// K2: h += x(64x3072) @ W1(3072x512), split-K with atomics.
// grid (8 N-tiles, 32 K-chunks of 96), block 256.
// Thread = (jg = tid&15 -> 4 j's, mg = tid>>4 -> 4 m's); 4x4 register tile.
// h must be pre-zeroed.
// ---------------------------------------------------------------------------
#define KCH 96
__global__ __launch_bounds__(256) void gemm1_kernel(
    const float* __restrict__ x, const float* __restrict__ W1,
    float* __restrict__ h) {
    const int jg = threadIdx.x & 15;
    const int mg = threadIdx.x >> 4;
    const int jbase = blockIdx.x * 64 + jg * 4;
    const int kbase = blockIdx.y * KCH;

    float acc[4][4];
#pragma unroll
    for (int i = 0; i < 4; ++i)
#pragma unroll
        for (int j = 0; j < 4; ++j) acc[i][j] = 0.f;

    const int m0 = mg * 4;
    for (int k = kbase; k < kbase + KCH; k += 4) {
        float4 wv[4];
#pragma unroll
        for (int kc = 0; kc < 4; ++kc)
            wv[kc] = *reinterpret_cast<const float4*>(W1 + (size_t)(k + kc) * HID + jbase);
        float4 xv[4];
#pragma unroll
        for (int mi = 0; mi < 4; ++mi)
            xv[mi] = *reinterpret_cast<const float4*>(x + (size_t)(m0 + mi) * (3 * H) + k);
#pragma unroll
        for (int mi = 0; mi < 4; ++mi) {
            acc[mi][0] += xv[mi].x * wv[0].x + xv[mi].y * wv[1].x + xv[mi].z * wv[2].x + xv[mi].w * wv[3].x;
            acc[mi][1] += xv[mi].x * wv[0].y + xv[mi].y * wv[1].y + xv[mi].z * wv[2].y + xv[mi].w * wv[3].y;
            acc[mi][2] += xv[mi].x * wv[0].z + xv[mi].y * wv[1].z + xv[mi].z * wv[2].z + xv[mi].w * wv[3].z;
            acc[mi][3] += xv[mi].x * wv[0].w + xv[mi].y * wv[1].w + xv[mi].z * wv[2].w + xv[mi].w * wv[3].w;
        }
    }

#pragma unroll
    for (int mi = 0; mi < 4; ++mi)
#pragma unroll
        for (int ji = 0; ji < 4; ++ji)
            atomicAdd(&h[(size_t)(m0 + mi) * HID + jbase + ji], acc[mi][ji]);
}

// ---------------------------------------------------------------------------
// K3: out[b] = leaky(BN(h[b] + b1)) @ W2 + b2. grid B, block 256.
// ---------------------------------------------------------------------------
__global__ __launch_bounds__(256) void head_kernel(
    const float* __restrict__ h, const float* __restrict__ b1,
    const float* __restrict__ gamma, const float* __restrict__ beta,
    const float* __restrict__ rm, const float* __restrict__ rv,
    const float* __restrict__ W2, const float* __restrict__ b2,
    float* __restrict__ out) {
    const int b = blockIdx.x;
    const int t = threadIdx.x;

    float c0 = 0.f, c1 = 0.f, c2 = 0.f;
    for (int j = t; j < HID; j += 256) {
        float v = (h[(size_t)b * HID + j] + b1[j] - rm[j]) * rsqrtf(rv[j] + EPS) * gamma[j] + beta[j];
        v = (v >= 0.f) ? v : 0.01f * v;
        c0 += v * W2[j * 3 + 0];
        c1 += v * W2[j * 3 + 1];
        c2 += v * W2[j * 3 + 2];
    }
#pragma unroll
    for (int off = 32; off > 0; off >>= 1) {
        c0 += __shfl_down(c0, off);
        c1 += __shfl_down(c1, off);
        c2 += __shfl_down(c2, off);
    }
    __shared__ float red[4][3];
    const int lane = t & 63, w = t >> 6;
    if (lane == 0) { red[w][0] = c0; red[w][1] = c1; red[w][2] = c2; }
    __syncthreads();
    if (t == 0) {
        out[b * 3 + 0] = red[0][0] + red[1][0] + red[2][0] + red[3][0] + b2[0];
        out[b * 3 + 1] = red[0][1] + red[1][1] + red[2][1] + red[3][1] + b2[1];
        out[b * 3 + 2] = red[0][2] + red[1][2] + red[2][2] + red[3][2] + b2[2];
    }
}

extern "C" void kernel_launch(void* const* d_in, const int* in_sizes, int n_in,
                              void* d_out, int out_size, void* d_ws, size_t ws_size,
                              hipStream_t stream) {
    const float* bert    = (const float*)d_in[0];
    const int*   offsets = (const int*)d_in[1];
    const float* W1      = (const float*)d_in[2];
    const float* b1      = (const float*)d_in[3];
    const float* gamma   = (const float*)d_in[4];
    const float* beta    = (const float*)d_in[5];
    const float* rm      = (const float*)d_in[6];
    const float* rv      = (const float*)d_in[7];
    const float* W2      = (const float*)d_in[8];
    const float* b2      = (const float*)d_in[9];
    float* out = (float*)d_out;

    float* x = (float*)d_ws;                                   // B x 3H = 768 KB
    float* h = (float*)((char*)d_ws + (size_t)B * 3 * H * 4);  // B x HID = 128 KB

    // zero x and h in one contiguous memset (they are adjacent in ws)
    hipMemsetAsync(d_ws, 0, (size_t)(B * 3 * H + B * HID) * sizeof(float), stream);

    dim3 g1(B, 3, NCH), t1(256);
    span_kernel<<<g1, t1, 0, stream>>>(bert, offsets, x);

    dim3 g2(HID / 64, (3 * H) / KCH), t2(256);
    gemm1_kernel<<<g2, t2, 0, stream>>>(x, W1, h);

    head_kernel<<<B, 256, 0, stream>>>(h, b1, gamma, beta, rm, rv, W2, b2, out);
}